// Round 1
// baseline (1222.789 us; speedup 1.0000x reference)
//
#include <hip/hip_runtime.h>
#include <cstdint>
#include <cstddef>

// QRNN fused pipeline for MI355X (gfx950).
// Shapes: B=32, S=2048, D_in=512, D_model=1024, D_mlp=1024, n_cls=128.
//
// Stages:
//  1) pack_x: x fp32 -> bf16 (optional, if ws big enough)
//  2) pack_u: U[j][0:512]=W[:,j], U[j][512:1024]=V[:,j]  (f cols j<1024, z cols j>=1024), bf16
//  3) qrnn_main: per (b, chunk of 128 steps, 64 d-cols): MFMA GEMM 128x128 (K=1024),
//     activations + segmented scan -> per-chunk (F,Z) aggregates
//  4) tail1: combine 16 chunk aggregates -> c[S-1]; o-gate at last step (fp32 exact); h = c*sigmoid(o)
//  5) mlp x3 (fp32 exact)

typedef __attribute__((ext_vector_type(8))) short short8;
typedef __attribute__((ext_vector_type(4))) float f32x4;

__device__ __forceinline__ unsigned short f2bf(float f) {
  unsigned int u = __float_as_uint(f);
  u += 0x7fffu + ((u >> 16) & 1u);   // round-to-nearest-even
  return (unsigned short)(u >> 16);
}

// ---------------- pack x: fp32 -> bf16, 33.5M elems, 4/thread ----------------
__global__ void pack_x_kernel(const float* __restrict__ x, unsigned short* __restrict__ xb) {
  int gid = blockIdx.x * 256 + threadIdx.x;   // 8,388,608 threads exactly
  float4 v = ((const float4*)x)[gid];
  ushort4 o;
  o.x = f2bf(v.x); o.y = f2bf(v.y); o.z = f2bf(v.z); o.w = f2bf(v.w);
  ((ushort4*)xb)[gid] = o;
}

// ---------------- pack U: [2048][1024] bf16 ----------------
__global__ void pack_u_kernel(const float* __restrict__ W, const float* __restrict__ V,
                              unsigned short* __restrict__ U) {
  int gid = blockIdx.x * 256 + threadIdx.x;   // 2,097,152 exactly
  int j = gid >> 10, k = gid & 1023;
  float v = (k < 512) ? W[(size_t)k * 3072 + j] : V[(size_t)(k - 512) * 3072 + j];
  U[gid] = f2bf(v);
}

// ---------------- main: GEMM (bf16 MFMA) + fused scan ----------------
// grid: (16 d-tiles, 16 chunks, 32 batch), block 256 (4 waves, 2x2 wave grid)
// block tile: M=128 timesteps x N=128 cols (64 f + 64 z), K=1024 (W-half + V-half)
__global__ __launch_bounds__(256) void qrnn_main(
    const unsigned short* __restrict__ xb, const float* __restrict__ xf, int use_bf,
    const unsigned short* __restrict__ U, const float* __restrict__ Vb,
    float* __restrict__ Fagg, float* __restrict__ Zagg) {
  __shared__ __align__(16) char smem[36864];
  unsigned short* As = (unsigned short*)smem;             // [128][72] bf16 (pad 72 -> 2-way max, free)
  unsigned short* Us = (unsigned short*)(smem + 18432);   // [128][72]

  const int dt = blockIdx.x;   // d-tile 0..15 (64 d each)
  const int cj = blockIdx.y;   // chunk 0..15
  const int b  = blockIdx.z;   // batch 0..31
  const int tid = threadIdx.x;
  const int lane = tid & 63;
  const int wid  = tid >> 6;
  const int wm = wid >> 1, wn = wid & 1;   // wave 2x2: each wave 64x64
  const int s0 = cj * 128;

  const int kcol  = (tid & 7) << 3;   // staging: 8 bf16 per thread per pass
  const int rbase = tid >> 3;         // 0..31

  f32x4 acc[4][4];
#pragma unroll
  for (int i = 0; i < 4; ++i)
#pragma unroll
    for (int j = 0; j < 4; ++j) acc[i][j] = f32x4{0.f, 0.f, 0.f, 0.f};

  const int mrow = wm * 64 + (lane & 15);
  const int ncol = wn * 64 + (lane & 15);

  for (int half = 0; half < 2; ++half) {       // 0: x[s]@W, 1: x[s-1]@V
    for (int kt = 0; kt < 8; ++kt) {           // K tiles of 64
      __syncthreads();
      // stage A: 128 rows x 64 k
#pragma unroll
      for (int p = 0; p < 4; ++p) {
        int r = rbase + p * 32;
        int sg = s0 + r - half;                // global timestep (V-half shifted by -1)
        uint4 v = make_uint4(0u, 0u, 0u, 0u);  // x[-1] = 0
        if (sg >= 0) {
          if (use_bf) {
            v = *(const uint4*)(xb + ((size_t)b * 2048 + sg) * 512 + kt * 64 + kcol);
          } else {
            const float* src = xf + ((size_t)b * 2048 + sg) * 512 + kt * 64 + kcol;
            float4 a0 = *(const float4*)src;
            float4 a1 = *(const float4*)(src + 4);
            v.x = (unsigned)f2bf(a0.x) | ((unsigned)f2bf(a0.y) << 16);
            v.y = (unsigned)f2bf(a0.z) | ((unsigned)f2bf(a0.w) << 16);
            v.z = (unsigned)f2bf(a1.x) | ((unsigned)f2bf(a1.y) << 16);
            v.w = (unsigned)f2bf(a1.z) | ((unsigned)f2bf(a1.w) << 16);
          }
        }
        *(uint4*)(As + r * 72 + kcol) = v;
      }
      // stage U: 128 cols x 64 k  (col c<64 -> f col dt*64+c ; c>=64 -> z col 1024+dt*64+c-64)
#pragma unroll
      for (int p = 0; p < 4; ++p) {
        int c = rbase + p * 32;
        int j = (c < 64) ? (dt * 64 + c) : (1024 + dt * 64 + (c - 64));
        uint4 v = *(const uint4*)(U + (size_t)j * 1024 + half * 512 + kt * 64 + kcol);
        *(uint4*)(Us + c * 72 + kcol) = v;
      }
      __syncthreads();
      // MFMA: 2 k-blocks of 32
#pragma unroll
      for (int kb = 0; kb < 2; ++kb) {
        const int ko = kb * 32 + ((lane >> 4) << 3);
        short8 afr[4], bfr[4];
#pragma unroll
        for (int i = 0; i < 4; ++i) {
          afr[i] = *(const short8*)(As + (mrow + i * 16) * 72 + ko);
          bfr[i] = *(const short8*)(Us + (ncol + i * 16) * 72 + ko);
        }
#pragma unroll
        for (int mt = 0; mt < 4; ++mt)
#pragma unroll
          for (int nt = 0; nt < 4; ++nt)
            acc[mt][nt] = __builtin_amdgcn_mfma_f32_16x16x32_bf16(afr[mt], bfr[nt], acc[mt][nt], 0, 0, 0);
      }
    }
  }
  __syncthreads();

  // ---- fused activations + scan (2 phases of 64 timesteps) ----
  float* sb   = (float*)smem;            // [64][132] fp32
  float* segF = (float*)(smem + 33792);  // [4][64]
  float* segZ = (float*)(smem + 34816);  // [4][64]
  float* Fr   = (float*)(smem + 35840);  // [64]
  float* Zr   = (float*)(smem + 36096);  // [64]
  if (tid < 64) { Fr[tid] = 1.f; Zr[tid] = 0.f; }

  const int d = tid & 63;
  const float vbf = Vb[dt * 64 + d];
  const float vbz = Vb[1024 + dt * 64 + d];

  for (int ph = 0; ph < 2; ++ph) {
    __syncthreads();
    if (wm == ph) {   // owner waves dump their C rows (pre-activation) to LDS
#pragma unroll
      for (int mt = 0; mt < 4; ++mt)
#pragma unroll
        for (int nt = 0; nt < 4; ++nt)
#pragma unroll
          for (int rg = 0; rg < 4; ++rg) {
            int r = mt * 16 + ((lane >> 4) << 2) + rg;      // 0..63 (local)
            int c = wn * 64 + nt * 16 + (lane & 15);        // 0..127
            sb[r * 132 + c] = acc[mt][nt][rg];
          }
    }
    __syncthreads();
    // activations: f = sigmoid(pre_f + vb), z = (1-f)*tanh(pre_z + vb)
#pragma unroll
    for (int i = 0; i < 16; ++i) {
      int t = wid + i * 4;
      float pf = sb[t * 132 + d] + vbf;
      float pz = sb[t * 132 + 64 + d] + vbz;
      float f = 1.f / (1.f + __expf(-pf));
      float z = (1.f - f) * tanhf(pz);
      sb[t * 132 + d] = f;
      sb[t * 132 + 64 + d] = z;
    }
    __syncthreads();
    // segmented scan: 4 segments of 16 steps per d
    {
      int seg = tid >> 6;
      float F = 1.f, Z = 0.f;
      for (int i = 0; i < 16; ++i) {
        int t = seg * 16 + i;
        float f = sb[t * 132 + d];
        float z = sb[t * 132 + 64 + d];
        F *= f; Z = f * Z + z;
      }
      segF[seg * 64 + d] = F;
      segZ[seg * 64 + d] = Z;
    }
    __syncthreads();
    if (tid < 64) {   // combine 4 segments in order into running aggregate
      float F = Fr[tid], Z = Zr[tid];
#pragma unroll
      for (int sgi = 0; sgi < 4; ++sgi) {
        float Fs = segF[sgi * 64 + tid], Zs = segZ[sgi * 64 + tid];
        Z = Fs * Z + Zs; F *= Fs;
      }
      Fr[tid] = F; Zr[tid] = Z;
    }
  }
  __syncthreads();
  if (tid < 64) {
    size_t o = ((size_t)b * 16 + cj) * 1024 + dt * 64 + tid;
    Fagg[o] = Fr[tid];
    Zagg[o] = Zr[tid];
  }
}

// ---------------- combine chunks + o gate + h (fp32 exact) ----------------
__global__ void tail1_kernel(const float* __restrict__ x, const float* __restrict__ W,
                             const float* __restrict__ V, const float* __restrict__ Vb,
                             const float* __restrict__ Fagg, const float* __restrict__ Zagg,
                             float* __restrict__ h) {
  int gid = blockIdx.x * 256 + threadIdx.x;   // 32768 = 32*1024
  int b = gid >> 10, d = gid & 1023;
  float c = 0.f;
#pragma unroll
  for (int j = 0; j < 16; ++j) {
    size_t o = ((size_t)b * 16 + j) * 1024 + d;
    c = Fagg[o] * c + Zagg[o];
  }
  const float* xl = x + ((size_t)b * 2048 + 2047) * 512;
  const float* xp = xl - 512;
  float po = Vb[2048 + d];
#pragma unroll 4
  for (int k = 0; k < 512; ++k) {
    po += xl[k] * W[(size_t)k * 3072 + 2048 + d];
    po += xp[k] * V[(size_t)k * 3072 + 2048 + d];
  }
  float og = 1.f / (1.f + __expf(-po));
  h[gid] = c * og;
}

// ---------------- MLP layer (fp32) ----------------
__global__ void mlp_kernel(const float* __restrict__ in, const float* __restrict__ Wt,
                           const float* __restrict__ bias, float* __restrict__ out,
                           int K, int N, int do_relu) {
  int gid = blockIdx.x * 256 + threadIdx.x;
  int b = gid / N, n = gid % N;
  const float* row = in + (size_t)b * K;
  float s = bias[n];
#pragma unroll 4
  for (int k = 0; k < K; ++k) s += row[k] * Wt[(size_t)k * N + n];
  if (do_relu) s = fmaxf(s, 0.f);
  out[gid] = s;
}

extern "C" void kernel_launch(void* const* d_in, const int* in_sizes, int n_in,
                              void* d_out, int out_size, void* d_ws, size_t ws_size,
                              hipStream_t stream) {
  const float* x  = (const float*)d_in[0];
  const float* W  = (const float*)d_in[1];
  const float* V  = (const float*)d_in[2];
  const float* Vb = (const float*)d_in[3];
  const float* W0 = (const float*)d_in[4];
  const float* b0 = (const float*)d_in[5];
  const float* W1 = (const float*)d_in[6];
  const float* b1 = (const float*)d_in[7];
  const float* W2 = (const float*)d_in[8];
  const float* b2 = (const float*)d_in[9];

  char* ws = (char*)d_ws;
  unsigned short* U = (unsigned short*)(ws);                         // 4 MiB
  float* Fagg = (float*)(ws + (size_t)4 * 1024 * 1024);              // 2 MiB
  float* Zagg = (float*)(ws + (size_t)6 * 1024 * 1024);              // 2 MiB
  float* h    = (float*)(ws + (size_t)8 * 1024 * 1024);              // 128 KiB
  float* q0   = (float*)(ws + (size_t)8 * 1024 * 1024 + 256 * 1024); // 128 KiB
  float* q1   = (float*)(ws + (size_t)8 * 1024 * 1024 + 512 * 1024); // 128 KiB
  unsigned short* xb = (unsigned short*)(ws + (size_t)16 * 1024 * 1024); // 64 MiB (optional)

  const size_t need_bf = (size_t)16 * 1024 * 1024 + (size_t)67108864;
  int use_bf = (ws_size >= need_bf) ? 1 : 0;   // constant across calls -> graph-safe

  if (use_bf) pack_x_kernel<<<32768, 256, 0, stream>>>(x, xb);
  pack_u_kernel<<<8192, 256, 0, stream>>>(W, V, U);
  qrnn_main<<<dim3(16, 16, 32), 256, 0, stream>>>(xb, x, use_bf, U, Vb, Fagg, Zagg);
  tail1_kernel<<<128, 256, 0, stream>>>(x, W, V, Vb, Fagg, Zagg, h);
  mlp_kernel<<<128, 256, 0, stream>>>(h, W0, b0, q0, 1024, 1024, 1);
  mlp_kernel<<<128, 256, 0, stream>>>(q0, W1, b1, q1, 1024, 1024, 1);
  mlp_kernel<<<16, 256, 0, stream>>>(q1, W2, b2, (float*)d_out, 1024, 128, 0);
}

// Round 2
// 895.771 us; speedup vs baseline: 1.3651x; 1.3651x over previous
//
#include <hip/hip_runtime.h>
#include <cstdint>
#include <cstddef>

// QRNN fused pipeline for MI355X (gfx950).
// B=32, S=2048, D_in=512, D_model=1024, D_mlp=1024, n_cls=128.
//
//  1) pack_x: x fp32 -> bf16 (if ws big enough)
//  2) pack_u: U[j][0:512]=W[:,j], U[j][512:1024]=V[:,j] (f cols j<1024, z cols >=1024)
//  3) qrnn_main: per (b, 128-step chunk, 64 d): 128x128 MFMA GEMM (K=1024 over 2 halves),
//     global_load_lds staging with XOR-swizzled LDS, in-register activations,
//     segmented scan -> per-chunk (F,Z) aggregates
//  4) head: combine 16 chunk aggs -> c[S-1]; o-gate (fp32, coalesced); h = c*sigmoid(o)
//  5) mlp x3 (fp32, coalesced)

typedef __attribute__((ext_vector_type(8))) short short8;
typedef __attribute__((ext_vector_type(4))) float f32x4;

__device__ __forceinline__ unsigned short f2bf(float f) {
  unsigned int u = __float_as_uint(f);
  u += 0x7fffu + ((u >> 16) & 1u);
  return (unsigned short)(u >> 16);
}

__device__ __forceinline__ void gload_lds16(const void* g, void* l) {
  __builtin_amdgcn_global_load_lds(
      (const __attribute__((address_space(1))) unsigned int*)g,
      (__attribute__((address_space(3))) unsigned int*)l, 16, 0, 0);
}

__device__ __forceinline__ float sigmoidf_fast(float x) {
  return 1.f / (1.f + __expf(-x));
}
__device__ __forceinline__ float tanhf_fast(float x) {
  float a = fabsf(x);
  float e = __expf(-2.f * a);
  float t = (1.f - e) / (1.f + e);
  return copysignf(t, x);
}

// ---------------- pack x: fp32 -> bf16 ----------------
__global__ void pack_x_kernel(const float* __restrict__ x, unsigned short* __restrict__ xb) {
  int gid = blockIdx.x * 256 + threadIdx.x;   // 8,388,608 threads
  float4 v = ((const float4*)x)[gid];
  ushort4 o;
  o.x = f2bf(v.x); o.y = f2bf(v.y); o.z = f2bf(v.z); o.w = f2bf(v.w);
  ((ushort4*)xb)[gid] = o;
}

// ---------------- pack U: [2048][1024] bf16 ----------------
__global__ void pack_u_kernel(const float* __restrict__ W, const float* __restrict__ V,
                              unsigned short* __restrict__ U) {
  int gid = blockIdx.x * 256 + threadIdx.x;   // 2,097,152
  int j = gid >> 10, k = gid & 1023;
  float v = (k < 512) ? W[(size_t)k * 3072 + j] : V[(size_t)(k - 512) * 3072 + j];
  U[gid] = f2bf(v);
}

// ---------------- main: MFMA GEMM + fused scan ----------------
// grid (16 dt, 16 cj, 32 b), block 256 (2x2 waves, 64x64 each)
// LDS K-loop: As/Us 128 rows x 64 bf16, row pitch 128B, chunk swizzle phys=c^(r&7)
__global__ __launch_bounds__(256) void qrnn_main(
    const unsigned short* __restrict__ xb, const float* __restrict__ xf, int use_bf,
    const unsigned short* __restrict__ U, const float* __restrict__ Vb,
    const unsigned short* __restrict__ zp,
    float* __restrict__ Fagg, float* __restrict__ Zagg) {
  __shared__ __align__(16) char smem[36864];
  char* As = smem;            // [128][128B]
  char* Us = smem + 16384;    // [128][128B]

  const int dt = blockIdx.x;
  const int cj = blockIdx.y;
  const int b  = blockIdx.z;
  const int tid = threadIdx.x;
  const int lane = tid & 63;
  const int wid  = tid >> 6;
  const int wm = wid >> 1, wn = wid & 1;
  const int s0 = cj * 128;

  f32x4 acc[4][4];
#pragma unroll
  for (int i = 0; i < 4; ++i)
#pragma unroll
    for (int j = 0; j < 4; ++j) acc[i][j] = f32x4{0.f, 0.f, 0.f, 0.f};

  const int mrow = wm * 64 + (lane & 15);
  const int ncol = wn * 64 + (lane & 15);

  // staging lane decomposition (global_load_lds path): lane -> (row-in-8, phys chunk)
  const int rloc = lane >> 3;     // 0..7
  const int pc   = lane & 7;      // phys chunk 0..7
  // fallback staging decomposition
  const int frow = tid >> 3;      // 0..31
  const int fc   = tid & 7;       // logical chunk

  for (int half = 0; half < 2; ++half) {       // 0: x[s]@W, 1: x[s-1]@V
    for (int kt = 0; kt < 8; ++kt) {
      __syncthreads();
      if (use_bf) {
        // ---- A via global_load_lds: wave wid stages rows [wid*32, wid*32+32) ----
#pragma unroll
        for (int p = 0; p < 4; ++p) {
          int r = wid * 32 + p * 8 + rloc;
          int c = pc ^ (r & 7);                // logical chunk
          int sg = s0 + r - half;
          const unsigned short* gp = (sg >= 0)
              ? xb + (((size_t)b * 2048 + sg) << 9) + kt * 64 + c * 8
              : zp + pc * 8;
          gload_lds16(gp, As + (wid * 32 + p * 8) * 128);
        }
      } else {
        // ---- fallback: fp32 load + convert, swizzled VGPR store ----
#pragma unroll
        for (int p = 0; p < 4; ++p) {
          int r = frow + p * 32;
          int sg = s0 + r - half;
          uint4 v = make_uint4(0u, 0u, 0u, 0u);
          if (sg >= 0) {
            const float* src = xf + (((size_t)b * 2048 + sg) << 9) + kt * 64 + fc * 8;
            float4 a0 = *(const float4*)src;
            float4 a1 = *(const float4*)(src + 4);
            v.x = (unsigned)f2bf(a0.x) | ((unsigned)f2bf(a0.y) << 16);
            v.y = (unsigned)f2bf(a0.z) | ((unsigned)f2bf(a0.w) << 16);
            v.z = (unsigned)f2bf(a1.x) | ((unsigned)f2bf(a1.y) << 16);
            v.w = (unsigned)f2bf(a1.z) | ((unsigned)f2bf(a1.w) << 16);
          }
          *(uint4*)(As + r * 128 + ((fc ^ (r & 7)) << 4)) = v;
        }
      }
      // ---- U via global_load_lds ----
#pragma unroll
      for (int p = 0; p < 4; ++p) {
        int cc = wid * 32 + p * 8 + rloc;
        int j = (cc < 64) ? (dt * 64 + cc) : (1024 + dt * 64 + (cc - 64));
        int c = pc ^ (cc & 7);
        const unsigned short* gp = U + ((size_t)j << 10) + half * 512 + kt * 64 + c * 8;
        gload_lds16(gp, Us + (wid * 32 + p * 8) * 128);
      }
      __syncthreads();
      // ---- MFMA: 2 k-blocks of 32 ----
#pragma unroll
      for (int kb = 0; kb < 2; ++kb) {
        const int cbase = kb * 4 + (lane >> 4);   // logical chunk
        short8 afr[4], bfr[4];
#pragma unroll
        for (int i = 0; i < 4; ++i) {
          int m = mrow + i * 16;
          afr[i] = *(const short8*)(As + m * 128 + ((cbase ^ (m & 7)) << 4));
          int n = ncol + i * 16;
          bfr[i] = *(const short8*)(Us + n * 128 + ((cbase ^ (n & 7)) << 4));
        }
#pragma unroll
        for (int mt = 0; mt < 4; ++mt)
#pragma unroll
          for (int nt = 0; nt < 4; ++nt)
            acc[mt][nt] = __builtin_amdgcn_mfma_f32_16x16x32_bf16(afr[mt], bfr[nt], acc[mt][nt], 0, 0, 0);
      }
    }
  }

  // ---- fused activations + scan (2 phases of 64 timesteps) ----
  // LDS: fA [64][68] f32 @0 (17408B), tzA [64][68] @17408, segF[4][64] @34816, segZ @35840
  float* fA   = (float*)smem;
  float* tzA  = (float*)(smem + 17408);
  float* segF = (float*)(smem + 34816);
  float* segZ = (float*)(smem + 35840);

  const int d = tid & 63;
  const int dl = lane & 15;
  float vb[4];
#pragma unroll
  for (int nt = 0; nt < 4; ++nt)
    vb[nt] = Vb[wn * 1024 + dt * 64 + nt * 16 + dl];

  float F_run = 1.f, Z_run = 0.f;

  for (int ph = 0; ph < 2; ++ph) {
    __syncthreads();
    if (wm == ph) {   // owner waves: activate in-register, dump to LDS
      float* dst = (wn == 0) ? fA : tzA;
#pragma unroll
      for (int mt = 0; mt < 4; ++mt)
#pragma unroll
        for (int nt = 0; nt < 4; ++nt)
#pragma unroll
          for (int rg = 0; rg < 4; ++rg) {
            int t = mt * 16 + ((lane >> 4) << 2) + rg;   // 0..63 phase-local
            int c = nt * 16 + dl;                        // 0..63 (d)
            float v = acc[mt][nt][rg] + vb[nt];
            v = (wn == 0) ? sigmoidf_fast(v) : tanhf_fast(v);
            dst[t * 68 + c] = v;
          }
    }
    __syncthreads();
    // segmented scan: 4 segments x 16 steps
    {
      int seg = tid >> 6;
      float F = 1.f, Z = 0.f;
#pragma unroll 4
      for (int i = 0; i < 16; ++i) {
        int t = seg * 16 + i;
        float f  = fA[t * 68 + d];
        float tz = tzA[t * 68 + d];
        float z = (1.f - f) * tz;
        Z = f * Z + z;
        F *= f;
      }
      segF[seg * 64 + d] = F;
      segZ[seg * 64 + d] = Z;
    }
    __syncthreads();
    if (tid < 64) {
#pragma unroll
      for (int sgi = 0; sgi < 4; ++sgi) {
        float Fs = segF[sgi * 64 + tid], Zs = segZ[sgi * 64 + tid];
        Z_run = Fs * Z_run + Zs;
        F_run *= Fs;
      }
    }
  }
  if (tid < 64) {
    size_t o = ((size_t)b * 16 + cj) * 1024 + dt * 64 + tid;
    Fagg[o] = F_run;
    Zagg[o] = Z_run;
  }
}

// ---------------- head: combine chunks + o gate + h (fp32, coalesced) ----------------
// grid (16 dtile, 8 btile), block 256 = 4 b x 64 d
__global__ void head_kernel(const float* __restrict__ x, const float* __restrict__ W,
                            const float* __restrict__ V, const float* __restrict__ Vb,
                            const float* __restrict__ Fagg, const float* __restrict__ Zagg,
                            float* __restrict__ h) {
  const int dl = threadIdx.x & 63;
  const int bl = threadIdx.x >> 6;
  const int d = blockIdx.x * 64 + dl;
  const int b = blockIdx.y * 4 + bl;

  const float* xl = x + ((size_t)b * 2048 + 2047) * 512;
  const float* xp = xl - 512;
  const float* Wc = W + 2048 + d;
  const float* Vc = V + 2048 + d;
  float po = Vb[2048 + d];
#pragma unroll 8
  for (int k = 0; k < 512; ++k) {
    po += xl[k] * Wc[(size_t)k * 3072];
    po += xp[k] * Vc[(size_t)k * 3072];
  }
  float c = 0.f;
#pragma unroll
  for (int j = 0; j < 16; ++j) {
    size_t o = (((size_t)b * 16 + j) << 10) + d;
    c = Fagg[o] * c + Zagg[o];
  }
  h[((size_t)b << 10) + d] = c * sigmoidf_fast(po);
}

// ---------------- MLP layer (fp32, coalesced) ----------------
// grid (N/64, B/4), block 256 = 4 b x 64 n
__global__ void mlp_kernel(const float* __restrict__ in, const float* __restrict__ Wt,
                           const float* __restrict__ bias, float* __restrict__ out,
                           int K, int N, int do_relu) {
  const int nl = threadIdx.x & 63;
  const int bl = threadIdx.x >> 6;
  const int n = blockIdx.x * 64 + nl;
  const int b = blockIdx.y * 4 + bl;
  const float* row = in + (size_t)b * K;
  const float* Wc = Wt + n;
  float s = bias[n];
#pragma unroll 8
  for (int k = 0; k < K; ++k) s += row[k] * Wc[(size_t)k * N];
  if (do_relu) s = fmaxf(s, 0.f);
  out[(size_t)b * N + n] = s;
}

extern "C" void kernel_launch(void* const* d_in, const int* in_sizes, int n_in,
                              void* d_out, int out_size, void* d_ws, size_t ws_size,
                              hipStream_t stream) {
  const float* x  = (const float*)d_in[0];
  const float* W  = (const float*)d_in[1];
  const float* V  = (const float*)d_in[2];
  const float* Vb = (const float*)d_in[3];
  const float* W0 = (const float*)d_in[4];
  const float* b0 = (const float*)d_in[5];
  const float* W1 = (const float*)d_in[6];
  const float* b1 = (const float*)d_in[7];
  const float* W2 = (const float*)d_in[8];
  const float* b2 = (const float*)d_in[9];

  char* ws = (char*)d_ws;
  unsigned short* U = (unsigned short*)(ws);                              // 4 MiB
  float* Fagg = (float*)(ws + (size_t)4 * 1024 * 1024);                   // 2 MiB
  float* Zagg = (float*)(ws + (size_t)6 * 1024 * 1024);                   // 2 MiB
  float* h    = (float*)(ws + (size_t)8 * 1024 * 1024);                   // 128 KiB
  float* q0   = (float*)(ws + (size_t)8 * 1024 * 1024 + 256 * 1024);
  float* q1   = (float*)(ws + (size_t)8 * 1024 * 1024 + 512 * 1024);
  unsigned short* zp = (unsigned short*)(ws + (size_t)8 * 1024 * 1024 + 768 * 1024); // 256 B zeros
  unsigned short* xb = (unsigned short*)(ws + (size_t)16 * 1024 * 1024);  // 64 MiB

  const size_t need_bf = (size_t)16 * 1024 * 1024 + (size_t)67108864;
  int use_bf = (ws_size >= need_bf) ? 1 : 0;   // constant across calls -> graph-safe

  hipMemsetAsync(zp, 0, 256, stream);
  if (use_bf) pack_x_kernel<<<32768, 256, 0, stream>>>(x, xb);
  pack_u_kernel<<<8192, 256, 0, stream>>>(W, V, U);
  qrnn_main<<<dim3(16, 16, 32), 256, 0, stream>>>(xb, x, use_bf, U, Vb, zp, Fagg, Zagg);
  head_kernel<<<dim3(16, 8), 256, 0, stream>>>(x, W, V, Vb, Fagg, Zagg, h);
  mlp_kernel<<<dim3(16, 8), 256, 0, stream>>>(h, W0, b0, q0, 1024, 1024, 1);
  mlp_kernel<<<dim3(16, 8), 256, 0, stream>>>(q0, W1, b1, q1, 1024, 1024, 1);
  mlp_kernel<<<dim3(2, 8), 256, 0, stream>>>(q1, W2, b2, (float*)d_out, 1024, 128, 0);
}

// Round 3
// 648.884 us; speedup vs baseline: 1.8845x; 1.3805x over previous
//
#include <hip/hip_runtime.h>
#include <cstdint>
#include <cstddef>

// QRNN fused pipeline for MI355X (gfx950).
// B=32, S=2048, D_in=512, D_model=1024, D_mlp=1024, n_cls=128.
//
//  1) pack_x: x fp32 -> bf16
//  2) pack_u: LDS-transposed pack: U[j][0:512]=W[:,j], U[j][512:1024]=V[:,j]
//  3) qrnn_main: per (b, 128-step chunk, 64 d): shared 129-row A window per kt,
//     two MFMA passes (W-half rows+1, V-half rows+0), in-register activations,
//     segmented scan -> per-chunk (F,Z) aggregates
//  4) head: K-split o-gate + chunk combine -> h
//  5) mlp x3 (K-split across waves, LDS reduce)

typedef __attribute__((ext_vector_type(8))) short short8;
typedef __attribute__((ext_vector_type(4))) float f32x4;

__device__ __forceinline__ unsigned short f2bf(float f) {
  unsigned int u = __float_as_uint(f);
  u += 0x7fffu + ((u >> 16) & 1u);
  return (unsigned short)(u >> 16);
}

__device__ __forceinline__ void gload_lds16(const void* g, void* l) {
  __builtin_amdgcn_global_load_lds(
      (const __attribute__((address_space(1))) unsigned int*)g,
      (__attribute__((address_space(3))) unsigned int*)l, 16, 0, 0);
}

__device__ __forceinline__ float sigmoidf_fast(float x) {
  return 1.f / (1.f + __expf(-x));
}
__device__ __forceinline__ float tanhf_fast(float x) {
  float a = fabsf(x);
  float e = __expf(-2.f * a);
  float t = (1.f - e) / (1.f + e);
  return copysignf(t, x);
}

// ---------------- pack x: fp32 -> bf16 ----------------
__global__ void pack_x_kernel(const float* __restrict__ x, unsigned short* __restrict__ xb) {
  int gid = blockIdx.x * 256 + threadIdx.x;   // 8,388,608 threads
  float4 v = ((const float4*)x)[gid];
  ushort4 o;
  o.x = f2bf(v.x); o.y = f2bf(v.y); o.z = f2bf(v.z); o.w = f2bf(v.w);
  ((ushort4*)xb)[gid] = o;
}

// ---------------- pack U via LDS transpose ----------------
// grid (32 j-tiles, 16 k-tiles), block 256. U[j][k] = k<512 ? W[k][j] : V[k-512][j]
__global__ void pack_u_kernel(const float* __restrict__ W, const float* __restrict__ V,
                              unsigned short* __restrict__ U) {
  __shared__ float T[64 * 65];
  const int j0 = blockIdx.x * 64;
  const int k0 = blockIdx.y * 64;
  const int jl = threadIdx.x & 63;
  const int q  = threadIdx.x >> 6;
  const float* src = (k0 < 512) ? (W + (size_t)k0 * 3072) : (V + (size_t)(k0 - 512) * 3072);
#pragma unroll 4
  for (int i = 0; i < 16; ++i) {
    int kl = q * 16 + i;
    T[kl * 65 + jl] = src[(size_t)kl * 3072 + j0 + jl];   // coalesced 256B
  }
  __syncthreads();
  const int kl = threadIdx.x & 63;
#pragma unroll 4
  for (int i = 0; i < 16; ++i) {
    int jj = q * 16 + i;
    U[(size_t)(j0 + jj) * 1024 + k0 + kl] = f2bf(T[kl * 65 + jj]);  // stride-65 read: conflict-free
  }
}

// ---------------- main: MFMA GEMM + fused scan ----------------
// grid (16 dt, 16 cj, 32 b), block 256 (2x2 waves, 64x64 each)
// A window: rows rr=0..128 <-> timestep s = s0-1+rr, 128B pitch, chunk swizzle phys=c^(rr&7)
// Pass h2=0 (x[s]@W): A rows m+1, U half 0. Pass h2=1 (x[s-1]@V): A rows m, U half 1.
__global__ __launch_bounds__(256) void qrnn_main(
    const unsigned short* __restrict__ xb, const float* __restrict__ xf, int use_bf,
    const unsigned short* __restrict__ U, const float* __restrict__ Vb,
    float* __restrict__ Fagg, float* __restrict__ Zagg) {
  __shared__ __align__(16) char smem[50176];
  char* As = smem;             // [129][128B] (17408B region)
  char* Us = smem + 17408;     // [2][128][128B]

  const int dt = blockIdx.x;
  const int cj = blockIdx.y;
  const int b  = blockIdx.z;
  const int tid = threadIdx.x;
  const int lane = tid & 63;
  const int wid  = tid >> 6;
  const int wm = wid >> 1, wn = wid & 1;
  const int s0 = cj * 128;

  f32x4 acc[4][4];
#pragma unroll
  for (int i = 0; i < 4; ++i)
#pragma unroll
    for (int j = 0; j < 4; ++j) acc[i][j] = f32x4{0.f, 0.f, 0.f, 0.f};

  const int mrow = wm * 64 + (lane & 15);
  const int ncol = wn * 64 + (lane & 15);
  const int rloc = lane >> 3;     // 0..7
  const int pc   = lane & 7;      // phys chunk
  const int frow = tid >> 3;      // fallback row 0..31
  const int fc   = tid & 7;

  for (int kt = 0; kt < 8; ++kt) {
    __syncthreads();
    if (use_bf) {
      // ---- A rows 0..127 (s = s0-1+rr; rr=0 may read 1KB before xb -> patched to 0 below)
#pragma unroll
      for (int p = 0; p < 4; ++p) {
        int rr = wid * 32 + p * 8 + rloc;
        int c = pc ^ (rr & 7);
        ptrdiff_t s = (ptrdiff_t)b * 2048 + (s0 - 1 + rr);
        gload_lds16(xb + s * 512 + kt * 64 + c * 8, As + (wid * 32 + p * 8) * 128);
      }
      if (tid < 8) {   // row 128, s = s0+127; chunk swizzle: 128&7==0 -> c=pc=tid
        gload_lds16(xb + ((size_t)b * 2048 + s0 + 127) * 512 + kt * 64 + tid * 8,
                    As + 128 * 128);
      }
    } else {
      // ---- fallback: fp32 load + convert ----
#pragma unroll
      for (int p = 0; p < 4; ++p) {
        int rr = frow + p * 32;
        int s = s0 - 1 + rr;
        uint4 v = make_uint4(0u, 0u, 0u, 0u);
        if (s >= 0) {
          const float* src = xf + (((size_t)b * 2048 + s) << 9) + kt * 64 + fc * 8;
          float4 a0 = *(const float4*)src;
          float4 a1 = *(const float4*)(src + 4);
          v.x = (unsigned)f2bf(a0.x) | ((unsigned)f2bf(a0.y) << 16);
          v.y = (unsigned)f2bf(a0.z) | ((unsigned)f2bf(a0.w) << 16);
          v.z = (unsigned)f2bf(a1.x) | ((unsigned)f2bf(a1.y) << 16);
          v.w = (unsigned)f2bf(a1.z) | ((unsigned)f2bf(a1.w) << 16);
        }
        *(uint4*)(As + rr * 128 + ((fc ^ (rr & 7)) << 4)) = v;
      }
      if (tid < 8) {
        const float* src = xf + (((size_t)b * 2048 + s0 + 127) << 9) + kt * 64 + tid * 8;
        float4 a0 = *(const float4*)src;
        float4 a1 = *(const float4*)(src + 4);
        uint4 v;
        v.x = (unsigned)f2bf(a0.x) | ((unsigned)f2bf(a0.y) << 16);
        v.y = (unsigned)f2bf(a0.z) | ((unsigned)f2bf(a0.w) << 16);
        v.z = (unsigned)f2bf(a1.x) | ((unsigned)f2bf(a1.y) << 16);
        v.w = (unsigned)f2bf(a1.z) | ((unsigned)f2bf(a1.w) << 16);
        *(uint4*)(As + 128 * 128 + (tid << 4)) = v;
      }
    }
    // ---- U: both halves ----
#pragma unroll
    for (int h2 = 0; h2 < 2; ++h2)
#pragma unroll
      for (int p = 0; p < 4; ++p) {
        int cc = wid * 32 + p * 8 + rloc;
        int j = (cc < 64) ? (dt * 64 + cc) : (1024 + dt * 64 + (cc - 64));
        int c = pc ^ (cc & 7);
        gload_lds16(U + ((size_t)j << 10) + h2 * 512 + kt * 64 + c * 8,
                    Us + h2 * 16384 + (wid * 32 + p * 8) * 128);
      }
    __syncthreads();
    if (cj == 0) {   // zero the s=-1 row (block-uniform branch)
      if (tid < 8) *(uint4*)(As + (tid << 4)) = make_uint4(0u, 0u, 0u, 0u);
      __syncthreads();
    }
    // ---- MFMA: 2 passes x 2 k-blocks ----
#pragma unroll
    for (int h2 = 0; h2 < 2; ++h2) {
      const char* Ub = Us + h2 * 16384;
#pragma unroll
      for (int kb = 0; kb < 2; ++kb) {
        const int cbase = kb * 4 + (lane >> 4);
        short8 afr[4], bfr[4];
#pragma unroll
        for (int i = 0; i < 4; ++i) {
          int rr = mrow + i * 16 + 1 - h2;
          afr[i] = *(const short8*)(As + rr * 128 + ((cbase ^ (rr & 7)) << 4));
          int n = ncol + i * 16;
          bfr[i] = *(const short8*)(Ub + n * 128 + ((cbase ^ (n & 7)) << 4));
        }
#pragma unroll
        for (int mt = 0; mt < 4; ++mt)
#pragma unroll
          for (int nt = 0; nt < 4; ++nt)
            acc[mt][nt] = __builtin_amdgcn_mfma_f32_16x16x32_bf16(afr[mt], bfr[nt], acc[mt][nt], 0, 0, 0);
      }
    }
  }

  // ---- fused activations + scan (2 phases of 64 timesteps) ----
  float* fA   = (float*)smem;            // [64][68]
  float* tzA  = (float*)(smem + 17408);  // [64][68]
  float* segF = (float*)(smem + 34816);  // [4][64]
  float* segZ = (float*)(smem + 35840);  // [4][64]

  const int d = tid & 63;
  const int dl = lane & 15;
  float vb[4];
#pragma unroll
  for (int nt = 0; nt < 4; ++nt)
    vb[nt] = Vb[wn * 1024 + dt * 64 + nt * 16 + dl];

  float F_run = 1.f, Z_run = 0.f;

  for (int ph = 0; ph < 2; ++ph) {
    __syncthreads();
    if (wm == ph) {
      float* dst = (wn == 0) ? fA : tzA;
#pragma unroll
      for (int mt = 0; mt < 4; ++mt)
#pragma unroll
        for (int nt = 0; nt < 4; ++nt)
#pragma unroll
          for (int rg = 0; rg < 4; ++rg) {
            int t = mt * 16 + ((lane >> 4) << 2) + rg;
            int c = nt * 16 + dl;
            float v = acc[mt][nt][rg] + vb[nt];
            v = (wn == 0) ? sigmoidf_fast(v) : tanhf_fast(v);
            dst[t * 68 + c] = v;
          }
    }
    __syncthreads();
    {
      int seg = tid >> 6;
      float F = 1.f, Z = 0.f;
#pragma unroll 4
      for (int i = 0; i < 16; ++i) {
        int t = seg * 16 + i;
        float f  = fA[t * 68 + d];
        float tz = tzA[t * 68 + d];
        float z = (1.f - f) * tz;
        Z = f * Z + z;
        F *= f;
      }
      segF[seg * 64 + d] = F;
      segZ[seg * 64 + d] = Z;
    }
    __syncthreads();
    if (tid < 64) {
#pragma unroll
      for (int sgi = 0; sgi < 4; ++sgi) {
        float Fs = segF[sgi * 64 + tid], Zs = segZ[sgi * 64 + tid];
        Z_run = Fs * Z_run + Zs;
        F_run *= Fs;
      }
    }
  }
  if (tid < 64) {
    size_t o = ((size_t)b * 16 + cj) * 1024 + dt * 64 + tid;
    Fagg[o] = F_run;
    Zagg[o] = Z_run;
  }
}

// ---------------- head: K-split o-gate + chunk combine ----------------
// grid (16 dtile, 32 b), block 256 = 64 d x 4 k-segments
__global__ void head_kernel(const float* __restrict__ x, const float* __restrict__ W,
                            const float* __restrict__ V, const float* __restrict__ Vb,
                            const float* __restrict__ Fagg, const float* __restrict__ Zagg,
                            float* __restrict__ h) {
  __shared__ float red[4][64];
  const int dl = threadIdx.x & 63;
  const int w  = threadIdx.x >> 6;
  const int d = blockIdx.x * 64 + dl;
  const int b = blockIdx.y;

  const float* xl = x + ((size_t)b * 2048 + 2047) * 512;
  const float* xp = xl - 512;
  const float* Wc = W + 2048 + d;
  const float* Vc = V + 2048 + d;
  float po = 0.f;
  const int k0 = w * 128;
#pragma unroll 8
  for (int k = k0; k < k0 + 128; ++k) {
    po += xl[k] * Wc[(size_t)k * 3072];
    po += xp[k] * Vc[(size_t)k * 3072];
  }
  red[w][dl] = po;
  __syncthreads();
  if (w == 0) {
    po = red[0][dl] + red[1][dl] + red[2][dl] + red[3][dl] + Vb[2048 + d];
    float c = 0.f;
#pragma unroll
    for (int j = 0; j < 16; ++j) {
      size_t o = (((size_t)b * 16 + j) << 10) + d;
      c = Fagg[o] * c + Zagg[o];
    }
    h[((size_t)b << 10) + d] = c * sigmoidf_fast(po);
  }
}

// ---------------- MLP layer: K-split across 4 waves ----------------
// grid (N/64, B), block 256 = 64 n x 4 k-segments
__global__ void mlp_kernel(const float* __restrict__ in, const float* __restrict__ Wt,
                           const float* __restrict__ bias, float* __restrict__ out,
                           int K, int N, int do_relu) {
  __shared__ float red[4][64];
  const int nl = threadIdx.x & 63;
  const int w  = threadIdx.x >> 6;
  const int n = blockIdx.x * 64 + nl;
  const int b = blockIdx.y;
  const float* row = in + (size_t)b * K;
  const float* Wc = Wt + n;
  float s = 0.f;
  const int kq = K >> 2;
  const int k0 = w * kq;
#pragma unroll 8
  for (int k = k0; k < k0 + kq; ++k) s += row[k] * Wc[(size_t)k * N];
  red[w][nl] = s;
  __syncthreads();
  if (w == 0) {
    s = red[0][nl] + red[1][nl] + red[2][nl] + red[3][nl] + bias[n];
    if (do_relu) s = fmaxf(s, 0.f);
    out[(size_t)b * N + n] = s;
  }
}

extern "C" void kernel_launch(void* const* d_in, const int* in_sizes, int n_in,
                              void* d_out, int out_size, void* d_ws, size_t ws_size,
                              hipStream_t stream) {
  const float* x  = (const float*)d_in[0];
  const float* W  = (const float*)d_in[1];
  const float* V  = (const float*)d_in[2];
  const float* Vb = (const float*)d_in[3];
  const float* W0 = (const float*)d_in[4];
  const float* b0 = (const float*)d_in[5];
  const float* W1 = (const float*)d_in[6];
  const float* b1 = (const float*)d_in[7];
  const float* W2 = (const float*)d_in[8];
  const float* b2 = (const float*)d_in[9];

  char* ws = (char*)d_ws;
  unsigned short* U = (unsigned short*)(ws);                              // 4 MiB
  float* Fagg = (float*)(ws + (size_t)4 * 1024 * 1024);                   // 2 MiB
  float* Zagg = (float*)(ws + (size_t)6 * 1024 * 1024);                   // 2 MiB
  float* h    = (float*)(ws + (size_t)8 * 1024 * 1024);                   // 128 KiB
  float* q0   = (float*)(ws + (size_t)8 * 1024 * 1024 + 256 * 1024);
  float* q1   = (float*)(ws + (size_t)8 * 1024 * 1024 + 512 * 1024);
  unsigned short* xb = (unsigned short*)(ws + (size_t)16 * 1024 * 1024);  // 64 MiB

  const size_t need_bf = (size_t)16 * 1024 * 1024 + (size_t)67108864;
  int use_bf = (ws_size >= need_bf) ? 1 : 0;   // constant across calls -> graph-safe

  if (use_bf) pack_x_kernel<<<32768, 256, 0, stream>>>(x, xb);
  pack_u_kernel<<<dim3(32, 16), 256, 0, stream>>>(W, V, U);
  qrnn_main<<<dim3(16, 16, 32), 256, 0, stream>>>(xb, x, use_bf, U, Vb, Fagg, Zagg);
  head_kernel<<<dim3(16, 32), 256, 0, stream>>>(x, W, V, Vb, Fagg, Zagg, h);
  mlp_kernel<<<dim3(16, 32), 256, 0, stream>>>(h, W0, b0, q0, 1024, 1024, 1);
  mlp_kernel<<<dim3(16, 32), 256, 0, stream>>>(q0, W1, b1, q1, 1024, 1024, 1);
  mlp_kernel<<<dim3(2, 32), 256, 0, stream>>>(q1, W2, b2, (float*)d_out, 1024, 128, 0);
}

// Round 4
// 637.399 us; speedup vs baseline: 1.9184x; 1.0180x over previous
//
#include <hip/hip_runtime.h>
#include <cstdint>
#include <cstddef>

// QRNN fused pipeline for MI355X (gfx950).
// B=32, S=2048, D_in=512, D_model=1024, D_mlp=1024, n_cls=128.
//
//  1) pack_x: x fp32 -> bf16
//  2) pack_u: LDS-transposed pack: U[j][0:512]=W[:,j], U[j][512:1024]=V[:,j]
//  3) qrnn_main: per (b, 256-step chunk, 64 d): 256x128 MFMA tile, shared 257-row
//     A window per kt, two MFMA passes (W rows+1, V rows+0), in-register
//     activations, segmented scan -> per-chunk (F,Z) aggregates
//  4) head: K-split o-gate + 8-chunk combine -> h
//  5) init_mlp: bias-preload; mlp x3 as K-split atomic GEMV (ReLU in consumer)

typedef __attribute__((ext_vector_type(8))) short short8;
typedef __attribute__((ext_vector_type(4))) float f32x4;

__device__ __forceinline__ unsigned short f2bf(float f) {
  unsigned int u = __float_as_uint(f);
  u += 0x7fffu + ((u >> 16) & 1u);
  return (unsigned short)(u >> 16);
}

__device__ __forceinline__ void gload_lds16(const void* g, void* l) {
  __builtin_amdgcn_global_load_lds(
      (const __attribute__((address_space(1))) unsigned int*)g,
      (__attribute__((address_space(3))) unsigned int*)l, 16, 0, 0);
}

__device__ __forceinline__ float sigmoidf_fast(float x) {
  return 1.f / (1.f + __expf(-x));
}
__device__ __forceinline__ float tanhf_fast(float x) {
  float a = fabsf(x);
  float e = __expf(-2.f * a);
  float t = (1.f - e) / (1.f + e);
  return copysignf(t, x);
}

// ---------------- pack x: fp32 -> bf16 ----------------
__global__ void pack_x_kernel(const float* __restrict__ x, unsigned short* __restrict__ xb) {
  int gid = blockIdx.x * 256 + threadIdx.x;   // 8,388,608 threads
  float4 v = ((const float4*)x)[gid];
  ushort4 o;
  o.x = f2bf(v.x); o.y = f2bf(v.y); o.z = f2bf(v.z); o.w = f2bf(v.w);
  ((ushort4*)xb)[gid] = o;
}

// ---------------- pack U via LDS transpose ----------------
__global__ void pack_u_kernel(const float* __restrict__ W, const float* __restrict__ V,
                              unsigned short* __restrict__ U) {
  __shared__ float T[64 * 65];
  const int j0 = blockIdx.x * 64;
  const int k0 = blockIdx.y * 64;
  const int jl = threadIdx.x & 63;
  const int q  = threadIdx.x >> 6;
  const float* src = (k0 < 512) ? (W + (size_t)k0 * 3072) : (V + (size_t)(k0 - 512) * 3072);
#pragma unroll 4
  for (int i = 0; i < 16; ++i) {
    int kl = q * 16 + i;
    T[kl * 65 + jl] = src[(size_t)kl * 3072 + j0 + jl];
  }
  __syncthreads();
  const int kl = threadIdx.x & 63;
#pragma unroll 4
  for (int i = 0; i < 16; ++i) {
    int jj = q * 16 + i;
    U[(size_t)(j0 + jj) * 1024 + k0 + kl] = f2bf(T[kl * 65 + jj]);
  }
}

// ---------------- main: 256x128 MFMA tile + fused scan ----------------
// grid (16 dt, 8 cj, 32 b), block 512 (4x2 waves of 64x64)
// A window rows rr=0..256 <-> s = s0-1+rr, 128B pitch, chunk swizzle phys=c^(rr&7)
// Us: [2 halves][128 rows][128B]
__global__ __launch_bounds__(512, 4) void qrnn_main(
    const unsigned short* __restrict__ xb, const float* __restrict__ xf, int use_bf,
    const unsigned short* __restrict__ U, const float* __restrict__ Vb,
    float* __restrict__ Fagg, float* __restrict__ Zagg) {
  __shared__ __align__(16) char smem[65664];
  char* As = smem;             // [257][128B] = 32896
  char* Us = smem + 32896;     // [2][128][128B] = 32768

  const int dt = blockIdx.x;
  const int cj = blockIdx.y;
  const int b  = blockIdx.z;
  const int tid = threadIdx.x;
  const int lane = tid & 63;
  const int wid  = tid >> 6;          // 0..7
  const int wm = wid >> 1, wn = wid & 1;   // 4 x 2 wave grid
  const int s0 = cj * 256;

  f32x4 acc[4][4];
#pragma unroll
  for (int i = 0; i < 4; ++i)
#pragma unroll
    for (int j = 0; j < 4; ++j) acc[i][j] = f32x4{0.f, 0.f, 0.f, 0.f};

  const int mrow = wm * 64 + (lane & 15);   // 0..255
  const int ncol = wn * 64 + (lane & 15);   // 0..127
  const int rloc = lane >> 3;     // 0..7
  const int pc   = lane & 7;      // phys chunk

  for (int kt = 0; kt < 8; ++kt) {
    __syncthreads();
    if (use_bf) {
      // ---- A rows 0..255 (s = s0-1+rr); rr=0,cj=0 reads 1KB before xb (safe ws), zeroed below
#pragma unroll
      for (int p = 0; p < 4; ++p) {
        int rr = wid * 32 + p * 8 + rloc;
        int c = pc ^ (rr & 7);
        ptrdiff_t s = (ptrdiff_t)b * 2048 + (s0 - 1 + rr);
        gload_lds16(xb + s * 512 + kt * 64 + c * 8, As + (wid * 32 + p * 8) * 128);
      }
      if (tid < 8) {   // row 256: s = s0+255; 256&7==0 -> c=pc=tid
        gload_lds16(xb + ((size_t)b * 2048 + s0 + 255) * 512 + kt * 64 + tid * 8,
                    As + 256 * 128);
      }
      // ---- U: 256 rows = 2 halves x 128 cols
#pragma unroll
      for (int p = 0; p < 4; ++p) {
        int cc = wid * 32 + p * 8 + rloc;       // 0..255
        int half = cc >> 7, col = cc & 127;
        int j = (col < 64) ? (dt * 64 + col) : (1024 + dt * 64 + (col - 64));
        int c = pc ^ (cc & 7);
        gload_lds16(U + ((size_t)j << 10) + half * 512 + kt * 64 + c * 8,
                    Us + (wid * 32 + p * 8) * 128);
      }
    } else {
      // ---- fallback: fp32 load + convert ----
#pragma unroll
      for (int p = 0; p < 4; ++p) {
        int rr = (tid >> 3) + p * 64;
        int fc = tid & 7;
        int s = s0 - 1 + rr;
        uint4 v = make_uint4(0u, 0u, 0u, 0u);
        if (s >= 0) {
          const float* src = xf + (((size_t)b * 2048 + s) << 9) + kt * 64 + fc * 8;
          float4 a0 = *(const float4*)src;
          float4 a1 = *(const float4*)(src + 4);
          v.x = (unsigned)f2bf(a0.x) | ((unsigned)f2bf(a0.y) << 16);
          v.y = (unsigned)f2bf(a0.z) | ((unsigned)f2bf(a0.w) << 16);
          v.z = (unsigned)f2bf(a1.x) | ((unsigned)f2bf(a1.y) << 16);
          v.w = (unsigned)f2bf(a1.z) | ((unsigned)f2bf(a1.w) << 16);
        }
        *(uint4*)(As + rr * 128 + ((fc ^ (rr & 7)) << 4)) = v;
      }
      if (tid < 8) {
        const float* src = xf + (((size_t)b * 2048 + s0 + 255) << 9) + kt * 64 + tid * 8;
        float4 a0 = *(const float4*)src;
        float4 a1 = *(const float4*)(src + 4);
        uint4 v;
        v.x = (unsigned)f2bf(a0.x) | ((unsigned)f2bf(a0.y) << 16);
        v.y = (unsigned)f2bf(a0.z) | ((unsigned)f2bf(a0.w) << 16);
        v.z = (unsigned)f2bf(a1.x) | ((unsigned)f2bf(a1.y) << 16);
        v.w = (unsigned)f2bf(a1.z) | ((unsigned)f2bf(a1.w) << 16);
        *(uint4*)(As + 256 * 128 + (tid << 4)) = v;
      }
      { // U fallback path not needed (U always bf16-packed) -> stage via vector loads
#pragma unroll
        for (int p = 0; p < 4; ++p) {
          int cc = (tid >> 3) + p * 64;
          int half = cc >> 7, col = cc & 127;
          int j = (col < 64) ? (dt * 64 + col) : (1024 + dt * 64 + (col - 64));
          int fc = tid & 7;
          int c = fc ^ (cc & 7);
          uint4 v = *(const uint4*)(U + ((size_t)j << 10) + half * 512 + kt * 64 + c * 8);
          *(uint4*)(Us + cc * 128 + (fc << 4)) = v;
        }
      }
    }
    __syncthreads();
    if (cj == 0) {   // zero the s=-1 row (block-uniform branch)
      if (tid < 8) *(uint4*)(As + (tid << 4)) = make_uint4(0u, 0u, 0u, 0u);
      __syncthreads();
    }
    // ---- MFMA: 2 passes (h2) x 2 k-blocks ----
#pragma unroll
    for (int h2 = 0; h2 < 2; ++h2) {
      const char* Ub = Us + h2 * 16384;
#pragma unroll
      for (int kb = 0; kb < 2; ++kb) {
        const int cbase = kb * 4 + (lane >> 4);
        short8 afr[4], bfr[4];
#pragma unroll
        for (int i = 0; i < 4; ++i) {
          int rr = mrow + i * 16 + 1 - h2;
          afr[i] = *(const short8*)(As + rr * 128 + ((cbase ^ (rr & 7)) << 4));
          int n = ncol + i * 16;
          bfr[i] = *(const short8*)(Ub + n * 128 + ((cbase ^ (n & 7)) << 4));
        }
#pragma unroll
        for (int mt = 0; mt < 4; ++mt)
#pragma unroll
          for (int nt = 0; nt < 4; ++nt)
            acc[mt][nt] = __builtin_amdgcn_mfma_f32_16x16x32_bf16(afr[mt], bfr[nt], acc[mt][nt], 0, 0, 0);
      }
    }
  }

  // ---- fused activations + scan (4 phases of 64 timesteps) ----
  float* fA   = (float*)smem;            // [64][68]
  float* tzA  = (float*)(smem + 17408);  // [64][68]
  float* segF = (float*)(smem + 34816);  // [8][64]
  float* segZ = (float*)(smem + 36864);  // [8][64]

  const int d = tid & 63;
  const int dl = lane & 15;
  float vb[4];
#pragma unroll
  for (int nt = 0; nt < 4; ++nt)
    vb[nt] = Vb[wn * 1024 + dt * 64 + nt * 16 + dl];

  float F_run = 1.f, Z_run = 0.f;

  for (int ph = 0; ph < 4; ++ph) {
    __syncthreads();
    if (wm == ph) {
      float* dst = (wn == 0) ? fA : tzA;
#pragma unroll
      for (int mt = 0; mt < 4; ++mt)
#pragma unroll
        for (int nt = 0; nt < 4; ++nt)
#pragma unroll
          for (int rg = 0; rg < 4; ++rg) {
            int t = mt * 16 + ((lane >> 4) << 2) + rg;   // 0..63 phase-local
            int c = nt * 16 + dl;
            float v = acc[mt][nt][rg] + vb[nt];
            v = (wn == 0) ? sigmoidf_fast(v) : tanhf_fast(v);
            dst[t * 68 + c] = v;
          }
    }
    __syncthreads();
    {
      int seg = tid >> 6;   // 0..7, 8 steps each
      float F = 1.f, Z = 0.f;
#pragma unroll
      for (int i = 0; i < 8; ++i) {
        int t = seg * 8 + i;
        float f  = fA[t * 68 + d];
        float tz = tzA[t * 68 + d];
        float z = (1.f - f) * tz;
        Z = f * Z + z;
        F *= f;
      }
      segF[seg * 64 + d] = F;
      segZ[seg * 64 + d] = Z;
    }
    __syncthreads();
    if (tid < 64) {
#pragma unroll
      for (int sgi = 0; sgi < 8; ++sgi) {
        float Fs = segF[sgi * 64 + tid], Zs = segZ[sgi * 64 + tid];
        Z_run = Fs * Z_run + Zs;
        F_run *= Fs;
      }
    }
  }
  if (tid < 64) {
    size_t o = (((size_t)b * 8 + cj) << 10) + dt * 64 + tid;
    Fagg[o] = F_run;
    Zagg[o] = Z_run;
  }
}

// ---------------- head: K-split o-gate + 8-chunk combine ----------------
// grid (16 dtile, 32 b), block 256 = 64 d x 4 k-segments
__global__ void head_kernel(const float* __restrict__ x, const float* __restrict__ W,
                            const float* __restrict__ V, const float* __restrict__ Vb,
                            const float* __restrict__ Fagg, const float* __restrict__ Zagg,
                            float* __restrict__ h) {
  __shared__ float red[4][64];
  const int dl = threadIdx.x & 63;
  const int w  = threadIdx.x >> 6;
  const int d = blockIdx.x * 64 + dl;
  const int b = blockIdx.y;

  const float* xl = x + ((size_t)b * 2048 + 2047) * 512;
  const float* xp = xl - 512;
  const float* Wc = W + 2048 + d;
  const float* Vc = V + 2048 + d;
  float po = 0.f;
  const int k0 = w * 128;
#pragma unroll 8
  for (int k = k0; k < k0 + 128; ++k) {
    po += xl[k] * Wc[(size_t)k * 3072];
    po += xp[k] * Vc[(size_t)k * 3072];
  }
  red[w][dl] = po;
  __syncthreads();
  if (w == 0) {
    po = red[0][dl] + red[1][dl] + red[2][dl] + red[3][dl] + Vb[2048 + d];
    float c = 0.f;
#pragma unroll
    for (int j = 0; j < 8; ++j) {
      size_t o = (((size_t)b * 8 + j) << 10) + d;
      c = Fagg[o] * c + Zagg[o];
    }
    h[((size_t)b << 10) + d] = c * sigmoidf_fast(po);
  }
}

// ---------------- MLP: bias preload + K-split atomic GEMV ----------------
__global__ void init_mlp_kernel(const float* __restrict__ b0, const float* __restrict__ b1,
                                const float* __restrict__ b2,
                                float* __restrict__ q0, float* __restrict__ q1,
                                float* __restrict__ out) {
  int gid = blockIdx.x * 256 + threadIdx.x;   // 32768
  q0[gid] = b0[gid & 1023];
  q1[gid] = b1[gid & 1023];
  if (gid < 4096) out[gid] = b2[gid & 127];
}

// grid (N/64, B, 4 ksplit), block 256 = 64 n x 4 waves. ReLU applied to INPUT.
__global__ void mlp_atomic_kernel(const float* __restrict__ in, const float* __restrict__ Wt,
                                  float* __restrict__ out, int K, int N, int relu_in) {
  __shared__ float red[4][64];
  const int nl = threadIdx.x & 63;
  const int w  = threadIdx.x >> 6;
  const int n = blockIdx.x * 64 + nl;
  const int b = blockIdx.y;
  const int k0 = blockIdx.z * (K >> 2) + w * (K >> 4);
  const float* row = in + (size_t)b * K;
  const float* Wc = Wt + n;
  float s = 0.f;
#pragma unroll 8
  for (int k = k0; k < k0 + (K >> 4); ++k) {
    float v = row[k];
    if (relu_in) v = fmaxf(v, 0.f);
    s += v * Wc[(size_t)k * N];
  }
  red[w][nl] = s;
  __syncthreads();
  if (w == 0) {
    s = red[0][nl] + red[1][nl] + red[2][nl] + red[3][nl];
    atomicAdd(&out[(size_t)b * N + n], s);
  }
}

extern "C" void kernel_launch(void* const* d_in, const int* in_sizes, int n_in,
                              void* d_out, int out_size, void* d_ws, size_t ws_size,
                              hipStream_t stream) {
  const float* x  = (const float*)d_in[0];
  const float* W  = (const float*)d_in[1];
  const float* V  = (const float*)d_in[2];
  const float* Vb = (const float*)d_in[3];
  const float* W0 = (const float*)d_in[4];
  const float* b0 = (const float*)d_in[5];
  const float* W1 = (const float*)d_in[6];
  const float* b1 = (const float*)d_in[7];
  const float* W2 = (const float*)d_in[8];
  const float* b2 = (const float*)d_in[9];

  char* ws = (char*)d_ws;
  unsigned short* U = (unsigned short*)(ws);                              // 4 MiB
  float* Fagg = (float*)(ws + (size_t)4 * 1024 * 1024);                   // 1 MiB used
  float* Zagg = (float*)(ws + (size_t)6 * 1024 * 1024);                   // 1 MiB used
  float* h    = (float*)(ws + (size_t)8 * 1024 * 1024);                   // 128 KiB
  float* q0   = (float*)(ws + (size_t)8 * 1024 * 1024 + 256 * 1024);
  float* q1   = (float*)(ws + (size_t)8 * 1024 * 1024 + 512 * 1024);
  unsigned short* xb = (unsigned short*)(ws + (size_t)16 * 1024 * 1024);  // 64 MiB

  const size_t need_bf = (size_t)16 * 1024 * 1024 + (size_t)67108864;
  int use_bf = (ws_size >= need_bf) ? 1 : 0;   // constant across calls -> graph-safe

  if (use_bf) pack_x_kernel<<<32768, 256, 0, stream>>>(x, xb);
  pack_u_kernel<<<dim3(32, 16), 256, 0, stream>>>(W, V, U);
  init_mlp_kernel<<<128, 256, 0, stream>>>(b0, b1, b2, q0, q1, (float*)d_out);
  qrnn_main<<<dim3(16, 8, 32), 512, 0, stream>>>(xb, x, use_bf, U, Vb, Fagg, Zagg);
  head_kernel<<<dim3(16, 32), 256, 0, stream>>>(x, W, V, Vb, Fagg, Zagg, h);
  mlp_atomic_kernel<<<dim3(16, 32, 4), 256, 0, stream>>>(h, W0, q0, 1024, 1024, 0);
  mlp_atomic_kernel<<<dim3(16, 32, 4), 256, 0, stream>>>(q0, W1, q1, 1024, 1024, 1);
  mlp_atomic_kernel<<<dim3(2, 32, 4), 256, 0, stream>>>(q1, W2, (float*)d_out, 1024, 128, 1);
}